// Round 6
// baseline (213.618 us; speedup 1.0000x reference)
//
#include <hip/hip_runtime.h>
#include <hip/hip_bf16.h>
#include <cstdint>
#include <cstddef>

#define N_O 50000
#define N_Q 50000
#define NE  1600000
// LATENT=128, HEADS=4, HEAD_DIM=32

#define EDGE_BLOCKS  (NE / 128)            // 12500 (2 waves x 64 edges, 128 thr)
#define VP_BLOCKS    ((N_O + 31) / 32)     // 1563  (32 rows per block)
#define RP_BLOCKS    ((N_Q + 128) / 128)   // 391
#define WCAP 264                           // attn LDS plane stride (floats)

// WvP planes live past the R0 high-water mark; runtime-checked.
#define WVP_OFF   38608768u
#define WVP_BYTES 65536u

typedef __attribute__((ext_vector_type(8)))  short short8;
typedef __attribute__((ext_vector_type(16))) float f32x16;

__device__ inline unsigned short f2bf(float x) {
    __hip_bfloat16 hb = __float2bfloat16(x);
    return *reinterpret_cast<unsigned short*>(&hb);
}

__device__ inline unsigned pk2(float a, float b) {
    __hip_bfloat162 t = __float22bfloat162_rn(make_float2(a, b));
    return *reinterpret_cast<unsigned*>(&t);
}

// ---------------------------------------------------------------------------
// pack (R2-proven, unchanged): block 0 = edge-MLP weights; blocks 1..8 =
// fragment-ordered Wv hi/lo bf16 planes for the MFMA vproj.
// ---------------------------------------------------------------------------
__global__ void pack_kernel(const float* __restrict__ W1, const float* __restrict__ b1,
                            const float* __restrict__ W2, const float* __restrict__ b2,
                            const float* __restrict__ log_sigma,
                            const float* __restrict__ Wv,
                            unsigned short* __restrict__ W1cT,
                            unsigned short* __restrict__ W2tb,
                            float* __restrict__ scal,
                            unsigned short* __restrict__ WvPhi,
                            unsigned short* __restrict__ WvPlo,
                            int vp_mfma) {
    int j = threadIdx.x;
    if (blockIdx.x == 0) {
        if (j < 128) {
            #pragma unroll
            for (int a = 0; a < 3; ++a) {
                W1cT[j * 8 + a]     = f2bf(W1[(3 + a) * 128 + j] + W1[a * 128 + j]); // pq coef
                W1cT[j * 8 + 3 + a] = f2bf(W1[(6 + a) * 128 + j] - W1[a * 128 + j]); // po coef
            }
            W1cT[j * 8 + 6] = f2bf(b1[j]);
            W1cT[j * 8 + 7] = 0;
            #pragma unroll
            for (int hd = 0; hd < 4; ++hd)
                W2tb[hd * 128 + j] = f2bf(W2[j * 4 + hd]);
        } else if (j == 128) {
            float sigma = expf(log_sigma[0]) + 1e-6f;
            scal[0] = 1.0f / (2.0f * sigma * sigma);
            scal[1] = b2[0]; scal[2] = b2[1]; scal[3] = b2[2]; scal[4] = b2[3];
        }
    } else if (vp_mfma) {
        // blocks 1..8: one frag-row (8 elems) per thread; 2048 frag-rows total
        int fr = (blockIdx.x - 1) * 256 + j;        // 0..2047
        int lane = fr & 63, i = lane & 31, g = lane >> 5;
        int ks = (fr >> 6) & 7, c = fr >> 9;
        #pragma unroll
        for (int e = 0; e < 8; ++e) {
            float w = Wv[(size_t)(16 * ks + 8 * g + e) * 128 + 32 * c + i];
            unsigned short hi = f2bf(w);
            float rem = w - __uint_as_float(((unsigned)hi) << 16);
            WvPhi[fr * 8 + e] = hi;
            WvPlo[fr * 8 + e] = f2bf(rem);
        }
    }
}

// ---------------------------------------------------------------------------
// rowptr body (proven, unchanged): rp[q] = lower_bound(dst,q)
// ---------------------------------------------------------------------------
__device__ void rowptr_body(int bid, const int* __restrict__ dst, int* __restrict__ rp) {
    int q = bid * 128 + threadIdx.x;
    if (q > N_Q) return;
    int lo = 0, hi = NE;
    while (lo < hi) {
        int mid = (lo + hi) >> 1;
        if (dst[mid] < q) lo = mid + 1; else hi = mid;
    }
    rp[q] = lo;
}

// ---------------------------------------------------------------------------
// vproj MFMA (R2-proven, unchanged): v = h_obs @ Wv + bv, 32-row tile per
// block, waves split output col-tiles, pre-packed A frags, 3-pass hi/lo.
// ---------------------------------------------------------------------------
__device__ void vproj_mfma_body(int tile, const float* __restrict__ h,
                                const unsigned short* __restrict__ WvPhi,
                                const unsigned short* __restrict__ WvPlo,
                                const float* __restrict__ bv,
                                unsigned short* __restrict__ v) {
    int lane = threadIdx.x & 63, wave = threadIdx.x >> 6;
    int i = lane & 31, g = lane >> 5;
    int n = tile * 32 + i;
    bool nok = (n < N_O);
    const float* hrow = h + (size_t)n * 128;

    short8 Bhi[8], Blo[8];
    #pragma unroll
    for (int ks = 0; ks < 8; ++ks) {
        float4 u0 = make_float4(0.f, 0.f, 0.f, 0.f), u1 = u0;
        if (nok) {
            u0 = *(const float4*)(hrow + 16 * ks + 8 * g);
            u1 = *(const float4*)(hrow + 16 * ks + 8 * g + 4);
        }
        float x[8] = {u0.x, u0.y, u0.z, u0.w, u1.x, u1.y, u1.z, u1.w};
        union { unsigned u[4]; short8 s; } ph, pl;
        #pragma unroll
        for (int p = 0; p < 4; ++p) {
            ph.u[p] = pk2(x[2 * p], x[2 * p + 1]);
            float e0 = x[2 * p]     - __uint_as_float(ph.u[p] << 16);
            float e1 = x[2 * p + 1] - __uint_as_float(ph.u[p] & 0xffff0000u);
            pl.u[p] = pk2(e0, e1);
        }
        Bhi[ks] = ph.s; Blo[ks] = pl.s;
    }

    #pragma unroll 1
    for (int cc = 0; cc < 2; ++cc) {
        int c = 2 * wave + cc;
        f32x16 acc;
        #pragma unroll
        for (int k = 0; k < 16; ++k) acc[k] = 0.f;
        #pragma unroll
        for (int ks = 0; ks < 8; ++ks) {
            int fr = (c * 8 + ks) * 64 + lane;
            short8 Ahi = *(const short8*)(WvPhi + fr * 8);
            short8 Alo = *(const short8*)(WvPlo + fr * 8);
            acc = __builtin_amdgcn_mfma_f32_32x32x16_bf16(Ahi, Bhi[ks], acc, 0, 0, 0);
            acc = __builtin_amdgcn_mfma_f32_32x32x16_bf16(Ahi, Blo[ks], acc, 0, 0, 0);
            acc = __builtin_amdgcn_mfma_f32_32x32x16_bf16(Alo, Bhi[ks], acc, 0, 0, 0);
        }
        if (nok) {
            #pragma unroll
            for (int q = 0; q < 4; ++q) {
                int vc = 32 * c + 8 * q + 4 * g;
                float4 bq = *(const float4*)(bv + vc);
                uint2 ov;
                ov.x = pk2(acc[4 * q + 0] + bq.x, acc[4 * q + 1] + bq.y);
                ov.y = pk2(acc[4 * q + 2] + bq.z, acc[4 * q + 3] + bq.w);
                *(uint2*)(v + (size_t)n * 128 + vc) = ov;
            }
        }
    }
}

// ---------------------------------------------------------------------------
// vproj fp32 fallback (R0-proven, verbatim): only if ws_size too tight.
// ---------------------------------------------------------------------------
__device__ void vproj_f32_body(int bid, const float* __restrict__ h,
                               const float* __restrict__ Wv,
                               const float* __restrict__ bv,
                               unsigned short* __restrict__ v,
                               float* Ash /* 32*132 floats */) {
    int t = threadIdx.x;          // 0..127
    int n0 = bid * 32;
    #pragma unroll
    for (int rep = 0; rep < 8; ++rep) {
        int idx = rep * 128 + t;
        int row = idx >> 5, c4 = (idx & 31) * 4;
        float4 val = make_float4(0.f, 0.f, 0.f, 0.f);
        if (n0 + row < N_O) val = *(const float4*)(h + (size_t)(n0 + row) * 128 + c4);
        float* d = &Ash[row * 132 + c4];
        d[0] = val.x; d[1] = val.y; d[2] = val.z; d[3] = val.w;
    }
    __syncthreads();

    int cg = t & 15, rg = t >> 4;
    int c0 = cg * 8, r0 = rg * 4;
    float acc[4][8];
    #pragma unroll
    for (int i = 0; i < 4; ++i)
        #pragma unroll
        for (int j = 0; j < 8; ++j) acc[i][j] = 0.f;

    const float4* Wv4 = (const float4*)Wv;
    for (int k = 0; k < 128; ++k) {
        float4 b0 = Wv4[k * 32 + cg * 2];
        float4 b1v = Wv4[k * 32 + cg * 2 + 1];
        float bb[8] = {b0.x, b0.y, b0.z, b0.w, b1v.x, b1v.y, b1v.z, b1v.w};
        #pragma unroll
        for (int i = 0; i < 4; ++i) {
            float a = Ash[(r0 + i) * 132 + k];
            #pragma unroll
            for (int j = 0; j < 8; ++j) acc[i][j] += a * bb[j];
        }
    }

    float bvv[8];
    #pragma unroll
    for (int j = 0; j < 8; ++j) bvv[j] = bv[c0 + j];
    #pragma unroll
    for (int i = 0; i < 4; ++i) {
        int n = n0 + r0 + i;
        if (n < N_O) {
            uint4 o;
            o.x = pk2(acc[i][0] + bvv[0], acc[i][1] + bvv[1]);
            o.y = pk2(acc[i][2] + bvv[2], acc[i][3] + bvv[3]);
            o.z = pk2(acc[i][4] + bvv[4], acc[i][5] + bvv[5]);
            o.w = pk2(acc[i][6] + bvv[6], acc[i][7] + bvv[7]);
            *(uint4*)(v + (size_t)n * 128 + c0) = o;
        }
    }
}

// ---------------------------------------------------------------------------
// edge body (R3-proven, unchanged): one wave = 64 distinct edges.
// ---------------------------------------------------------------------------
__device__ void edge_body(int bid, const float* __restrict__ pos_obs,
                          const float* __restrict__ pos_query,
                          const int* __restrict__ src, const int* __restrict__ dst,
                          const unsigned short* __restrict__ W1cT,
                          const unsigned short* __restrict__ W2tb,
                          const float* __restrict__ scal,
                          float* __restrict__ logitsT,
                          unsigned char* smem /* 2*8448 B */) {
    int t = threadIdx.x;
    int wave = t >> 6, lane = t & 63;
    int i = lane & 31, h = lane >> 5;
    unsigned char* myrow = smem + wave * 8448 + i * 264;

    short8 zero8;
    #pragma unroll
    for (int k = 0; k < 8; ++k) zero8[k] = 0;

    // own-edge gathers (all issued upfront; the only long-latency chain)
    int e = bid * 128 + wave * 64 + lane;
    int s = src[e], d = dst[e];
    float pox = pos_obs[s * 3 + 0], poy = pos_obs[s * 3 + 1], poz = pos_obs[s * 3 + 2];
    float pqx = pos_query[d * 3 + 0], pqy = pos_query[d * 3 + 1], pqz = pos_query[d * 3 + 2];
    float rx = pqx - pox, ry = pqy - poy, rz = pqz - poz;
    float dist2 = rx * rx + ry * ry + rz * rz;

    // packed edge attrs: [pqx,pqy][pqz,pox][poy,poz][1.0,0]
    unsigned pk[4];
    pk[0] = pk2(pqx, pqy);
    pk[1] = pk2(pqz, pox);
    pk[2] = pk2(poy, poz);
    pk[3] = 0x00003F80u;

    unsigned pb[4];
    #pragma unroll
    for (int p = 0; p < 4; ++p) pb[p] = (unsigned)__shfl_xor((int)pk[p], 32);

    union { unsigned u[4]; short8 s8; } beaA, beaB;
    #pragma unroll
    for (int p = 0; p < 4; ++p) {
        beaA.u[p] = h ? 0u : pk[p];     // set A: edges base+0..31
        beaB.u[p] = h ? 0u : pb[p];     // set B: edges base+32..63
    }

    short8 a1[4];
    #pragma unroll
    for (int b = 0; b < 4; ++b)
        a1[b] = (h == 0) ? *(const short8*)(W1cT + (32 * b + i) * 8) : zero8;

    short8 a2[8];
    #pragma unroll
    for (int m = 0; m < 8; ++m)
        a2[m] = (i < 4) ? *(const short8*)(W2tb + i * 128 + m * 16 + h * 8) : zero8;

    float headA[4], headB[4];

    #pragma unroll
    for (int set = 0; set < 2; ++set) {
        const short8 bea = set ? beaB.s8 : beaA.s8;

        // GEMM1: 4 independent MFMAs
        f32x16 c1[4];
        #pragma unroll
        for (int b = 0; b < 4; ++b) {
            #pragma unroll
            for (int k = 0; k < 16; ++k) c1[b][k] = 0.0f;
            c1[b] = __builtin_amdgcn_mfma_f32_32x32x16_bf16(a1[b], bea, c1[b], 0, 0, 0);
        }

        // relu -> bf16 -> LDS (proven layout: hidden 32b+8s+4h+r at 64b+16s+8h)
        #pragma unroll
        for (int b = 0; b < 4; ++b) {
            #pragma unroll
            for (int s_ = 0; s_ < 4; ++s_) {
                float x0 = fmaxf(c1[b][4 * s_ + 0], 0.f);
                float x1 = fmaxf(c1[b][4 * s_ + 1], 0.f);
                float x2 = fmaxf(c1[b][4 * s_ + 2], 0.f);
                float x3 = fmaxf(c1[b][4 * s_ + 3], 0.f);
                uint2 w;
                w.x = pk2(x0, x1);
                w.y = pk2(x2, x3);
                *(uint2*)(myrow + 64 * b + 16 * s_ + 8 * h) = w;
            }
        }

        // GEMM2: two independent 4-chains (halve exposed MFMA latency)
        f32x16 cx, cy;
        #pragma unroll
        for (int k = 0; k < 16; ++k) { cx[k] = 0.0f; cy[k] = 0.0f; }
        #pragma unroll
        for (int m = 0; m < 8; m += 2) {
            uint2 lo0 = *(const uint2*)(myrow + 32 * m + 16 * h);
            uint2 hi0 = *(const uint2*)(myrow + 32 * m + 16 * h + 8);
            uint2 lo1 = *(const uint2*)(myrow + 32 * (m + 1) + 16 * h);
            uint2 hi1 = *(const uint2*)(myrow + 32 * (m + 1) + 16 * h + 8);
            union { unsigned int u[4]; short8 s; } b0, b1u;
            b0.u[0] = lo0.x; b0.u[1] = lo0.y; b0.u[2] = hi0.x; b0.u[3] = hi0.y;
            b1u.u[0] = lo1.x; b1u.u[1] = lo1.y; b1u.u[2] = hi1.x; b1u.u[3] = hi1.y;
            cx = __builtin_amdgcn_mfma_f32_32x32x16_bf16(a2[m],     b0.s,  cx, 0, 0, 0);
            cy = __builtin_amdgcn_mfma_f32_32x32x16_bf16(a2[m + 1], b1u.s, cy, 0, 0, 0);
        }
        float* hd = set ? headB : headA;
        #pragma unroll
        for (int r = 0; r < 4; ++r) hd[r] = cx[r] + cy[r];
    }

    // store: every lane writes its OWN edge's 4 logits (coalesced 256B/plane)
    float pen = dist2 * scal[0];
    #pragma unroll
    for (int r = 0; r < 4; ++r) {
        float vB = __shfl_xor(headB[r], 32);       // lane 32+i <- lane i's set-B head
        float val = (h ? vB : headA[r]) + scal[1 + r] - pen;
        logitsT[(size_t)r * NE + e] = val;
    }
}

// ---------------------------------------------------------------------------
// fused: edge | vproj | rowptr partitioned by blockIdx. 128 threads,
// 16896 B LDS. (128,4): pin VGPR <=128.
// ---------------------------------------------------------------------------
__global__ __launch_bounds__(128, 4) void fused_kernel(
        const float* __restrict__ pos_obs, const float* __restrict__ pos_query,
        const int* __restrict__ src, const int* __restrict__ dst,
        const unsigned short* __restrict__ W1cT,
        const unsigned short* __restrict__ W2tb,
        const float* __restrict__ scal, float* __restrict__ logitsT,
        const float* __restrict__ h_obs, const float* __restrict__ Wv,
        const float* __restrict__ bv, unsigned short* __restrict__ vbuf,
        int* __restrict__ rp,
        const unsigned short* __restrict__ WvPhi,
        const unsigned short* __restrict__ WvPlo,
        int vp_mfma) {
    __shared__ __align__(16) unsigned char smem[16896];  // 2*8448 == 32*132*4
    int b = blockIdx.x;
    if (b < EDGE_BLOCKS) {
        edge_body(b, pos_obs, pos_query, src, dst, W1cT, W2tb, scal, logitsT, smem);
    } else if (b < EDGE_BLOCKS + VP_BLOCKS) {
        int tile = b - EDGE_BLOCKS;
        if (vp_mfma) vproj_mfma_body(tile, h_obs, WvPhi, WvPlo, bv, vbuf);
        else         vproj_f32_body(tile, h_obs, Wv, bv, vbuf, (float*)smem);
    } else {
        rowptr_body(b - EDGE_BLOCKS - VP_BLOCKS, dst, rp);
    }
}

// ---------------------------------------------------------------------------
// attn v2 (hardened): one wave per query. Max/stage/sum passes unchanged.
// Quarter-wave gather: lane = 16*sub + c; sub handles edge e+sub, c covers
// elements 8c..8c+7 (ONE uint4 = 16 B of the 256 B v row; 1 load inst per
// 4 edges instead of 4). 32-bit shift addressing ((src<<8)+(c<<4)),
// per-lane single head hc=c>>2, weight = in-bounds indexed LDS scalar read
// (no negative-offset base pointer). Butterfly sum over sub groups
// (shfl_xor 16,32), coalesced 512 B store from 32 lanes. cnt>256 generic
// path verbatim (Poisson(32) never takes it; correctness only).
// ---------------------------------------------------------------------------
__global__ __launch_bounds__(256) void attn_kernel(const __hip_bfloat162* __restrict__ vb,
                                                   const float* __restrict__ logitsT,
                                                   const int* __restrict__ src,
                                                   const int* __restrict__ rp,
                                                   float* __restrict__ out) {
    __shared__ __align__(16) float wsh[4 * 4 * WCAP];   // 16896 B
    int t = threadIdx.x;
    int lane = t & 63, wave = t >> 6;
    int q = blockIdx.x * 4 + wave;
    int s0 = rp[q], s1 = rp[q + 1];
    int cnt = s1 - s0;
    int h = lane >> 4, i = lane & 15;
    const float* lp = logitsT + (size_t)h * NE;

    float m = -INFINITY;
    for (int e = s0 + i; e < s1; e += 16) m = fmaxf(m, lp[e]);
    #pragma unroll
    for (int off = 8; off; off >>= 1) m = fmaxf(m, __shfl_xor(m, off));

    if (cnt <= 256) {
        float* wpb = wsh + wave * (4 * WCAP) + h * WCAP;
        float sum = 0.f;
        for (int e = s0 + i; e < s1; e += 16) {
            float w = __expf(lp[e] - m);
            wpb[e - s0] = w;
            sum += w;
        }
        #pragma unroll
        for (int off = 8; off; off >>= 1) sum += __shfl_xor(sum, off);
        float r = 1.0f / (sum + 1e-16f);

        int sub = lane >> 4, c = lane & 15;
        int hc = c >> 2;
        float rh = __shfl(r, hc << 4);
        const float* wpb2 = wsh + wave * (4 * WCAP) + hc * WCAP;   // in-bounds base
        const unsigned char* vb8 = (const unsigned char*)vb;
        unsigned coff = (unsigned)(c << 4);

        float a0 = 0.f, a1 = 0.f, a2 = 0.f, a3 = 0.f;
        float a4 = 0.f, a5 = 0.f, a6 = 0.f, a7 = 0.f;
        int e = s0;
        for (; e + 4 <= s1; e += 4) {
            int es = e + sub;
            unsigned sidx = (unsigned)src[es];
            uint4 vv = *(const uint4*)(vb8 + ((sidx << 8) + coff));
            float w = wpb2[es - s0];
            a0 += w * __uint_as_float(vv.x << 16);
            a1 += w * __uint_as_float(vv.x & 0xffff0000u);
            a2 += w * __uint_as_float(vv.y << 16);
            a3 += w * __uint_as_float(vv.y & 0xffff0000u);
            a4 += w * __uint_as_float(vv.z << 16);
            a5 += w * __uint_as_float(vv.z & 0xffff0000u);
            a6 += w * __uint_as_float(vv.w << 16);
            a7 += w * __uint_as_float(vv.w & 0xffff0000u);
        }
        int rem = s1 - e;
        if (sub < rem) {
            int es = e + sub;
            unsigned sidx = (unsigned)src[es];
            uint4 vv = *(const uint4*)(vb8 + ((sidx << 8) + coff));
            float w = wpb2[es - s0];
            a0 += w * __uint_as_float(vv.x << 16);
            a1 += w * __uint_as_float(vv.x & 0xffff0000u);
            a2 += w * __uint_as_float(vv.y << 16);
            a3 += w * __uint_as_float(vv.y & 0xffff0000u);
            a4 += w * __uint_as_float(vv.z << 16);
            a5 += w * __uint_as_float(vv.z & 0xffff0000u);
            a6 += w * __uint_as_float(vv.w << 16);
            a7 += w * __uint_as_float(vv.w & 0xffff0000u);
        }
        // combine the 4 sub groups (butterfly over lane bits 4,5)
        #pragma unroll
        for (int off = 16; off <= 32; off <<= 1) {
            a0 += __shfl_xor(a0, off);
            a1 += __shfl_xor(a1, off);
            a2 += __shfl_xor(a2, off);
            a3 += __shfl_xor(a3, off);
            a4 += __shfl_xor(a4, off);
            a5 += __shfl_xor(a5, off);
            a6 += __shfl_xor(a6, off);
            a7 += __shfl_xor(a7, off);
        }
        if (sub < 2) {
            float4 o = sub ? make_float4(a4 * rh, a5 * rh, a6 * rh, a7 * rh)
                           : make_float4(a0 * rh, a1 * rh, a2 * rh, a3 * rh);
            *(float4*)(out + (size_t)q * 128 + c * 8 + sub * 4) = o;
        }
    } else {
        float sum = 0.f;
        for (int e = s0 + i; e < s1; e += 16) sum += __expf(lp[e] - m);
        #pragma unroll
        for (int off = 8; off; off >>= 1) sum += __shfl_xor(sum, off);
        float r = 1.0f / (sum + 1e-16f);
        float acc0 = 0.f, acc1 = 0.f;

        int e = s0;
        for (; e < s1 && (e & 3); ++e) {
            float w = __expf(lp[e] - m);
            float2 f = __bfloat1622float2(vb[(size_t)src[e] * 64 + lane]);
            acc0 += w * f.x; acc1 += w * f.y;
        }
        for (; e + 4 <= s1; e += 4) {
            float4 l4 = *(const float4*)(lp + e);
            int4 s4 = *(const int4*)(src + e);
            float w0 = __expf(l4.x - m);
            float w1 = __expf(l4.y - m);
            float w2 = __expf(l4.z - m);
            float w3 = __expf(l4.w - m);
            float2 f0 = __bfloat1622float2(vb[(size_t)s4.x * 64 + lane]);
            float2 f1 = __bfloat1622float2(vb[(size_t)s4.y * 64 + lane]);
            float2 f2 = __bfloat1622float2(vb[(size_t)s4.z * 64 + lane]);
            float2 f3 = __bfloat1622float2(vb[(size_t)s4.w * 64 + lane]);
            acc0 += w0 * f0.x + w1 * f1.x + w2 * f2.x + w3 * f3.x;
            acc1 += w0 * f0.y + w1 * f1.y + w2 * f2.y + w3 * f3.y;
        }
        for (; e < s1; ++e) {
            float w = __expf(lp[e] - m);
            float2 f = __bfloat1622float2(vb[(size_t)src[e] * 64 + lane]);
            acc0 += w * f.x; acc1 += w * f.y;
        }
        *(float2*)(out + (size_t)q * 128 + lane * 2) = make_float2(acc0 * r, acc1 * r);
    }
}

// ---------------------------------------------------------------------------
// ws layout: R0-proven; WvP planes past the high-water mark, runtime-checked.
// ---------------------------------------------------------------------------
extern "C" void kernel_launch(void* const* d_in, const int* in_sizes, int n_in,
                              void* d_out, int out_size, void* d_ws, size_t ws_size,
                              hipStream_t stream) {
    const float* h_obs     = (const float*)d_in[0];
    const float* pos_obs   = (const float*)d_in[1];
    const float* pos_query = (const float*)d_in[2];
    const int*   src       = (const int*)d_in[3];
    const int*   dst       = (const int*)d_in[4];
    const float* W1        = (const float*)d_in[5];
    const float* b1        = (const float*)d_in[6];
    const float* W2        = (const float*)d_in[7];
    const float* b2        = (const float*)d_in[8];
    const float* Wv        = (const float*)d_in[9];
    const float* bv        = (const float*)d_in[10];
    const float* log_sigma = (const float*)d_in[11];
    float* out = (float*)d_out;

    char* ws = (char*)d_ws;
    int*            rp      = (int*)(ws + 0);                   // 50001 ints  (end 200,004)
    float*          scal    = (float*)(ws + 200192);            // 8 floats    (end 200,224)
    unsigned short* W1cT    = (unsigned short*)(ws + 200256);   // 1024 bf16   (end 202,304)
    unsigned short* W2tb    = (unsigned short*)(ws + 202304);   // 512 bf16    (end 203,328)
    unsigned short* vbuf    = (unsigned short*)(ws + 208640);   // 6.4M bf16   (end 13,008,640)
    float*          logitsT = (float*)(ws + 13008768);          // 6.4M floats (end 38,608,768)
    unsigned short* WvPhi   = (unsigned short*)(ws + WVP_OFF);           // 32 KB
    unsigned short* WvPlo   = (unsigned short*)(ws + WVP_OFF + 32768);   // 32 KB

    int vp_mfma = (ws_size >= (size_t)WVP_OFF + WVP_BYTES) ? 1 : 0;

    hipLaunchKernelGGL(pack_kernel, dim3(9), dim3(256), 0, stream,
                       W1, b1, W2, b2, log_sigma, Wv, W1cT, W2tb, scal,
                       WvPhi, WvPlo, vp_mfma);
    hipLaunchKernelGGL(fused_kernel, dim3(EDGE_BLOCKS + VP_BLOCKS + RP_BLOCKS),
                       dim3(128), 0, stream,
                       pos_obs, pos_query, src, dst, W1cT, W2tb, scal, logitsT,
                       h_obs, Wv, bv, vbuf, rp, WvPhi, WvPlo, vp_mfma);
    hipLaunchKernelGGL(attn_kernel, dim3(N_Q / 4), dim3(256), 0, stream,
                       (const __hip_bfloat162*)vbuf, logitsT, src, rp, out);
}

// Round 7
// 206.123 us; speedup vs baseline: 1.0364x; 1.0364x over previous
//
#include <hip/hip_runtime.h>
#include <hip/hip_bf16.h>
#include <cstdint>
#include <cstddef>

#define N_O 50000
#define N_Q 50000
#define NE  1600000
// LATENT=128, HEADS=4, HEAD_DIM=32

#define EDGE_BLOCKS  (NE / 128)            // 12500 (2 waves x 64 edges, 128 thr)
#define VP_BLOCKS    ((N_O + 31) / 32)     // 1563  (32 rows per block)
#define RP_BLOCKS    ((N_Q + 128) / 128)   // 391
#define WCAP 264                           // attn LDS plane stride (floats)

// WvP planes live past the R0 high-water mark; runtime-checked.
#define WVP_OFF   38608768u
#define WVP_BYTES 65536u

typedef __attribute__((ext_vector_type(8)))  short short8;
typedef __attribute__((ext_vector_type(16))) float f32x16;

__device__ inline unsigned short f2bf(float x) {
    __hip_bfloat16 hb = __float2bfloat16(x);
    return *reinterpret_cast<unsigned short*>(&hb);
}

__device__ inline unsigned pk2(float a, float b) {
    __hip_bfloat162 t = __float22bfloat162_rn(make_float2(a, b));
    return *reinterpret_cast<unsigned*>(&t);
}

// ---------------------------------------------------------------------------
// pack (R2-proven, unchanged): block 0 = edge-MLP weights; blocks 1..8 =
// fragment-ordered Wv hi/lo bf16 planes for the MFMA vproj.
// ---------------------------------------------------------------------------
__global__ void pack_kernel(const float* __restrict__ W1, const float* __restrict__ b1,
                            const float* __restrict__ W2, const float* __restrict__ b2,
                            const float* __restrict__ log_sigma,
                            const float* __restrict__ Wv,
                            unsigned short* __restrict__ W1cT,
                            unsigned short* __restrict__ W2tb,
                            float* __restrict__ scal,
                            unsigned short* __restrict__ WvPhi,
                            unsigned short* __restrict__ WvPlo,
                            int vp_mfma) {
    int j = threadIdx.x;
    if (blockIdx.x == 0) {
        if (j < 128) {
            #pragma unroll
            for (int a = 0; a < 3; ++a) {
                W1cT[j * 8 + a]     = f2bf(W1[(3 + a) * 128 + j] + W1[a * 128 + j]); // pq coef
                W1cT[j * 8 + 3 + a] = f2bf(W1[(6 + a) * 128 + j] - W1[a * 128 + j]); // po coef
            }
            W1cT[j * 8 + 6] = f2bf(b1[j]);
            W1cT[j * 8 + 7] = 0;
            #pragma unroll
            for (int hd = 0; hd < 4; ++hd)
                W2tb[hd * 128 + j] = f2bf(W2[j * 4 + hd]);
        } else if (j == 128) {
            float sigma = expf(log_sigma[0]) + 1e-6f;
            scal[0] = 1.0f / (2.0f * sigma * sigma);
            scal[1] = b2[0]; scal[2] = b2[1]; scal[3] = b2[2]; scal[4] = b2[3];
        }
    } else if (vp_mfma) {
        // blocks 1..8: one frag-row (8 elems) per thread; 2048 frag-rows total
        int fr = (blockIdx.x - 1) * 256 + j;        // 0..2047
        int lane = fr & 63, i = lane & 31, g = lane >> 5;
        int ks = (fr >> 6) & 7, c = fr >> 9;
        #pragma unroll
        for (int e = 0; e < 8; ++e) {
            float w = Wv[(size_t)(16 * ks + 8 * g + e) * 128 + 32 * c + i];
            unsigned short hi = f2bf(w);
            float rem = w - __uint_as_float(((unsigned)hi) << 16);
            WvPhi[fr * 8 + e] = hi;
            WvPlo[fr * 8 + e] = f2bf(rem);
        }
    }
}

// ---------------------------------------------------------------------------
// rowptr body (proven, unchanged): rp[q] = lower_bound(dst,q)
// ---------------------------------------------------------------------------
__device__ void rowptr_body(int bid, const int* __restrict__ dst, int* __restrict__ rp) {
    int q = bid * 128 + threadIdx.x;
    if (q > N_Q) return;
    int lo = 0, hi = NE;
    while (lo < hi) {
        int mid = (lo + hi) >> 1;
        if (dst[mid] < q) lo = mid + 1; else hi = mid;
    }
    rp[q] = lo;
}

// ---------------------------------------------------------------------------
// vproj MFMA (R2-proven, unchanged): v = h_obs @ Wv + bv, 32-row tile per
// block, waves split output col-tiles, pre-packed A frags, 3-pass hi/lo.
// ---------------------------------------------------------------------------
__device__ void vproj_mfma_body(int tile, const float* __restrict__ h,
                                const unsigned short* __restrict__ WvPhi,
                                const unsigned short* __restrict__ WvPlo,
                                const float* __restrict__ bv,
                                unsigned short* __restrict__ v) {
    int lane = threadIdx.x & 63, wave = threadIdx.x >> 6;
    int i = lane & 31, g = lane >> 5;
    int n = tile * 32 + i;
    bool nok = (n < N_O);
    const float* hrow = h + (size_t)n * 128;

    short8 Bhi[8], Blo[8];
    #pragma unroll
    for (int ks = 0; ks < 8; ++ks) {
        float4 u0 = make_float4(0.f, 0.f, 0.f, 0.f), u1 = u0;
        if (nok) {
            u0 = *(const float4*)(hrow + 16 * ks + 8 * g);
            u1 = *(const float4*)(hrow + 16 * ks + 8 * g + 4);
        }
        float x[8] = {u0.x, u0.y, u0.z, u0.w, u1.x, u1.y, u1.z, u1.w};
        union { unsigned u[4]; short8 s; } ph, pl;
        #pragma unroll
        for (int p = 0; p < 4; ++p) {
            ph.u[p] = pk2(x[2 * p], x[2 * p + 1]);
            float e0 = x[2 * p]     - __uint_as_float(ph.u[p] << 16);
            float e1 = x[2 * p + 1] - __uint_as_float(ph.u[p] & 0xffff0000u);
            pl.u[p] = pk2(e0, e1);
        }
        Bhi[ks] = ph.s; Blo[ks] = pl.s;
    }

    #pragma unroll 1
    for (int cc = 0; cc < 2; ++cc) {
        int c = 2 * wave + cc;
        f32x16 acc;
        #pragma unroll
        for (int k = 0; k < 16; ++k) acc[k] = 0.f;
        #pragma unroll
        for (int ks = 0; ks < 8; ++ks) {
            int fr = (c * 8 + ks) * 64 + lane;
            short8 Ahi = *(const short8*)(WvPhi + fr * 8);
            short8 Alo = *(const short8*)(WvPlo + fr * 8);
            acc = __builtin_amdgcn_mfma_f32_32x32x16_bf16(Ahi, Bhi[ks], acc, 0, 0, 0);
            acc = __builtin_amdgcn_mfma_f32_32x32x16_bf16(Ahi, Blo[ks], acc, 0, 0, 0);
            acc = __builtin_amdgcn_mfma_f32_32x32x16_bf16(Alo, Bhi[ks], acc, 0, 0, 0);
        }
        if (nok) {
            #pragma unroll
            for (int q = 0; q < 4; ++q) {
                int vc = 32 * c + 8 * q + 4 * g;
                float4 bq = *(const float4*)(bv + vc);
                uint2 ov;
                ov.x = pk2(acc[4 * q + 0] + bq.x, acc[4 * q + 1] + bq.y);
                ov.y = pk2(acc[4 * q + 2] + bq.z, acc[4 * q + 3] + bq.w);
                *(uint2*)(v + (size_t)n * 128 + vc) = ov;
            }
        }
    }
}

// ---------------------------------------------------------------------------
// vproj fp32 fallback (R0-proven, verbatim): only if ws_size too tight.
// ---------------------------------------------------------------------------
__device__ void vproj_f32_body(int bid, const float* __restrict__ h,
                               const float* __restrict__ Wv,
                               const float* __restrict__ bv,
                               unsigned short* __restrict__ v,
                               float* Ash /* 32*132 floats */) {
    int t = threadIdx.x;          // 0..127
    int n0 = bid * 32;
    #pragma unroll
    for (int rep = 0; rep < 8; ++rep) {
        int idx = rep * 128 + t;
        int row = idx >> 5, c4 = (idx & 31) * 4;
        float4 val = make_float4(0.f, 0.f, 0.f, 0.f);
        if (n0 + row < N_O) val = *(const float4*)(h + (size_t)(n0 + row) * 128 + c4);
        float* d = &Ash[row * 132 + c4];
        d[0] = val.x; d[1] = val.y; d[2] = val.z; d[3] = val.w;
    }
    __syncthreads();

    int cg = t & 15, rg = t >> 4;
    int c0 = cg * 8, r0 = rg * 4;
    float acc[4][8];
    #pragma unroll
    for (int i = 0; i < 4; ++i)
        #pragma unroll
        for (int j = 0; j < 8; ++j) acc[i][j] = 0.f;

    const float4* Wv4 = (const float4*)Wv;
    for (int k = 0; k < 128; ++k) {
        float4 b0 = Wv4[k * 32 + cg * 2];
        float4 b1v = Wv4[k * 32 + cg * 2 + 1];
        float bb[8] = {b0.x, b0.y, b0.z, b0.w, b1v.x, b1v.y, b1v.z, b1v.w};
        #pragma unroll
        for (int i = 0; i < 4; ++i) {
            float a = Ash[(r0 + i) * 132 + k];
            #pragma unroll
            for (int j = 0; j < 8; ++j) acc[i][j] += a * bb[j];
        }
    }

    float bvv[8];
    #pragma unroll
    for (int j = 0; j < 8; ++j) bvv[j] = bv[c0 + j];
    #pragma unroll
    for (int i = 0; i < 4; ++i) {
        int n = n0 + r0 + i;
        if (n < N_O) {
            uint4 o;
            o.x = pk2(acc[i][0] + bvv[0], acc[i][1] + bvv[1]);
            o.y = pk2(acc[i][2] + bvv[2], acc[i][3] + bvv[3]);
            o.z = pk2(acc[i][4] + bvv[4], acc[i][5] + bvv[5]);
            o.w = pk2(acc[i][6] + bvv[6], acc[i][7] + bvv[7]);
            *(uint4*)(v + (size_t)n * 128 + c0) = o;
        }
    }
}

// ---------------------------------------------------------------------------
// edge body (R3-proven, unchanged): one wave = 64 distinct edges.
// ---------------------------------------------------------------------------
__device__ void edge_body(int bid, const float* __restrict__ pos_obs,
                          const float* __restrict__ pos_query,
                          const int* __restrict__ src, const int* __restrict__ dst,
                          const unsigned short* __restrict__ W1cT,
                          const unsigned short* __restrict__ W2tb,
                          const float* __restrict__ scal,
                          float* __restrict__ logitsT,
                          unsigned char* smem /* 2*8448 B */) {
    int t = threadIdx.x;
    int wave = t >> 6, lane = t & 63;
    int i = lane & 31, h = lane >> 5;
    unsigned char* myrow = smem + wave * 8448 + i * 264;

    short8 zero8;
    #pragma unroll
    for (int k = 0; k < 8; ++k) zero8[k] = 0;

    // own-edge gathers (all issued upfront; the only long-latency chain)
    int e = bid * 128 + wave * 64 + lane;
    int s = src[e], d = dst[e];
    float pox = pos_obs[s * 3 + 0], poy = pos_obs[s * 3 + 1], poz = pos_obs[s * 3 + 2];
    float pqx = pos_query[d * 3 + 0], pqy = pos_query[d * 3 + 1], pqz = pos_query[d * 3 + 2];
    float rx = pqx - pox, ry = pqy - poy, rz = pqz - poz;
    float dist2 = rx * rx + ry * ry + rz * rz;

    // packed edge attrs: [pqx,pqy][pqz,pox][poy,poz][1.0,0]
    unsigned pk[4];
    pk[0] = pk2(pqx, pqy);
    pk[1] = pk2(pqz, pox);
    pk[2] = pk2(poy, poz);
    pk[3] = 0x00003F80u;

    unsigned pb[4];
    #pragma unroll
    for (int p = 0; p < 4; ++p) pb[p] = (unsigned)__shfl_xor((int)pk[p], 32);

    union { unsigned u[4]; short8 s8; } beaA, beaB;
    #pragma unroll
    for (int p = 0; p < 4; ++p) {
        beaA.u[p] = h ? 0u : pk[p];     // set A: edges base+0..31
        beaB.u[p] = h ? 0u : pb[p];     // set B: edges base+32..63
    }

    short8 a1[4];
    #pragma unroll
    for (int b = 0; b < 4; ++b)
        a1[b] = (h == 0) ? *(const short8*)(W1cT + (32 * b + i) * 8) : zero8;

    short8 a2[8];
    #pragma unroll
    for (int m = 0; m < 8; ++m)
        a2[m] = (i < 4) ? *(const short8*)(W2tb + i * 128 + m * 16 + h * 8) : zero8;

    float headA[4], headB[4];

    #pragma unroll
    for (int set = 0; set < 2; ++set) {
        const short8 bea = set ? beaB.s8 : beaA.s8;

        // GEMM1: 4 independent MFMAs
        f32x16 c1[4];
        #pragma unroll
        for (int b = 0; b < 4; ++b) {
            #pragma unroll
            for (int k = 0; k < 16; ++k) c1[b][k] = 0.0f;
            c1[b] = __builtin_amdgcn_mfma_f32_32x32x16_bf16(a1[b], bea, c1[b], 0, 0, 0);
        }

        // relu -> bf16 -> LDS (proven layout: hidden 32b+8s+4h+r at 64b+16s+8h)
        #pragma unroll
        for (int b = 0; b < 4; ++b) {
            #pragma unroll
            for (int s_ = 0; s_ < 4; ++s_) {
                float x0 = fmaxf(c1[b][4 * s_ + 0], 0.f);
                float x1 = fmaxf(c1[b][4 * s_ + 1], 0.f);
                float x2 = fmaxf(c1[b][4 * s_ + 2], 0.f);
                float x3 = fmaxf(c1[b][4 * s_ + 3], 0.f);
                uint2 w;
                w.x = pk2(x0, x1);
                w.y = pk2(x2, x3);
                *(uint2*)(myrow + 64 * b + 16 * s_ + 8 * h) = w;
            }
        }

        // GEMM2: two independent 4-chains (halve exposed MFMA latency)
        f32x16 cx, cy;
        #pragma unroll
        for (int k = 0; k < 16; ++k) { cx[k] = 0.0f; cy[k] = 0.0f; }
        #pragma unroll
        for (int m = 0; m < 8; m += 2) {
            uint2 lo0 = *(const uint2*)(myrow + 32 * m + 16 * h);
            uint2 hi0 = *(const uint2*)(myrow + 32 * m + 16 * h + 8);
            uint2 lo1 = *(const uint2*)(myrow + 32 * (m + 1) + 16 * h);
            uint2 hi1 = *(const uint2*)(myrow + 32 * (m + 1) + 16 * h + 8);
            union { unsigned int u[4]; short8 s; } b0, b1u;
            b0.u[0] = lo0.x; b0.u[1] = lo0.y; b0.u[2] = hi0.x; b0.u[3] = hi0.y;
            b1u.u[0] = lo1.x; b1u.u[1] = lo1.y; b1u.u[2] = hi1.x; b1u.u[3] = hi1.y;
            cx = __builtin_amdgcn_mfma_f32_32x32x16_bf16(a2[m],     b0.s,  cx, 0, 0, 0);
            cy = __builtin_amdgcn_mfma_f32_32x32x16_bf16(a2[m + 1], b1u.s, cy, 0, 0, 0);
        }
        float* hd = set ? headB : headA;
        #pragma unroll
        for (int r = 0; r < 4; ++r) hd[r] = cx[r] + cy[r];
    }

    // store: every lane writes its OWN edge's 4 logits (coalesced 256B/plane)
    float pen = dist2 * scal[0];
    #pragma unroll
    for (int r = 0; r < 4; ++r) {
        float vB = __shfl_xor(headB[r], 32);       // lane 32+i <- lane i's set-B head
        float val = (h ? vB : headA[r]) + scal[1 + r] - pen;
        logitsT[(size_t)r * NE + e] = val;
    }
}

// ---------------------------------------------------------------------------
// fused: NEW dispatch order [rowptr | vproj | edge] (bodies unchanged).
// rowptr's 21-step dependent-load chains and vproj now launch FIRST and
// overlap the 12500 uniform edge blocks, instead of forming a serial tail
// that delays attn. 128 threads, 16896 B LDS, (128,4).
// ---------------------------------------------------------------------------
__global__ __launch_bounds__(128, 4) void fused_kernel(
        const float* __restrict__ pos_obs, const float* __restrict__ pos_query,
        const int* __restrict__ src, const int* __restrict__ dst,
        const unsigned short* __restrict__ W1cT,
        const unsigned short* __restrict__ W2tb,
        const float* __restrict__ scal, float* __restrict__ logitsT,
        const float* __restrict__ h_obs, const float* __restrict__ Wv,
        const float* __restrict__ bv, unsigned short* __restrict__ vbuf,
        int* __restrict__ rp,
        const unsigned short* __restrict__ WvPhi,
        const unsigned short* __restrict__ WvPlo,
        int vp_mfma) {
    __shared__ __align__(16) unsigned char smem[16896];  // 2*8448 == 32*132*4
    int b = blockIdx.x;
    if (b < RP_BLOCKS) {
        rowptr_body(b, dst, rp);
    } else if (b < RP_BLOCKS + VP_BLOCKS) {
        int tile = b - RP_BLOCKS;
        if (vp_mfma) vproj_mfma_body(tile, h_obs, WvPhi, WvPlo, bv, vbuf);
        else         vproj_f32_body(tile, h_obs, Wv, bv, vbuf, (float*)smem);
    } else {
        edge_body(b - RP_BLOCKS - VP_BLOCKS, pos_obs, pos_query, src, dst,
                  W1cT, W2tb, scal, logitsT, smem);
    }
}

// ---------------------------------------------------------------------------
// attn (R3-proven, verbatim revert): one wave per query; LDS-staged exp
// weights; full-wave per-edge row gather (ONE contiguous 256 B segment per
// instruction — R6 proved 4-segment variants regress); 8-deep pipeline.
// ---------------------------------------------------------------------------
__global__ __launch_bounds__(256) void attn_kernel(const __hip_bfloat162* __restrict__ vb,
                                                   const float* __restrict__ logitsT,
                                                   const int* __restrict__ src,
                                                   const int* __restrict__ rp,
                                                   float* __restrict__ out) {
    __shared__ __align__(16) float wsh[4 * 4 * WCAP];   // 16896 B
    int t = threadIdx.x;
    int lane = t & 63, wave = t >> 6;
    int q = blockIdx.x * 4 + wave;
    int s0 = rp[q], s1 = rp[q + 1];
    int cnt = s1 - s0;
    int h = lane >> 4, i = lane & 15;
    const float* lp = logitsT + (size_t)h * NE;

    float m = -INFINITY;
    for (int e = s0 + i; e < s1; e += 16) m = fmaxf(m, lp[e]);
    #pragma unroll
    for (int off = 8; off; off >>= 1) m = fmaxf(m, __shfl_xor(m, off));

    float acc0 = 0.f, acc1 = 0.f, r;

    if (cnt <= 256) {
        int s0a = s0 & ~3;
        float* wpb = wsh + wave * (4 * WCAP) + h * WCAP;
        float sum = 0.f;
        for (int e = s0 + i; e < s1; e += 16) {
            float w = __expf(lp[e] - m);
            wpb[e - s0a] = w;
            sum += w;
        }
        #pragma unroll
        for (int off = 8; off; off >>= 1) sum += __shfl_xor(sum, off);
        r = 1.0f / (sum + 1e-16f);

        int e = s0;
        int e1 = (s0 + 3) & ~3; if (e1 > s1) e1 = s1;
        for (; e < e1; ++e) {
            float w = wpb[e - s0a];
            float2 f = __bfloat1622float2(vb[(size_t)src[e] * 64 + lane]);
            acc0 += w * f.x; acc1 += w * f.y;
        }
        for (; e + 8 <= s1; e += 8) {
            float4 wa = *(const float4*)(wpb + (e - s0a));
            float4 wb = *(const float4*)(wpb + (e - s0a) + 4);
            int4 sa = *(const int4*)(src + e);
            int4 sb = *(const int4*)(src + e + 4);
            float2 f0 = __bfloat1622float2(vb[(size_t)sa.x * 64 + lane]);
            float2 f1 = __bfloat1622float2(vb[(size_t)sa.y * 64 + lane]);
            float2 f2 = __bfloat1622float2(vb[(size_t)sa.z * 64 + lane]);
            float2 f3 = __bfloat1622float2(vb[(size_t)sa.w * 64 + lane]);
            float2 f4 = __bfloat1622float2(vb[(size_t)sb.x * 64 + lane]);
            float2 f5 = __bfloat1622float2(vb[(size_t)sb.y * 64 + lane]);
            float2 f6 = __bfloat1622float2(vb[(size_t)sb.z * 64 + lane]);
            float2 f7 = __bfloat1622float2(vb[(size_t)sb.w * 64 + lane]);
            acc0 += wa.x * f0.x + wa.y * f1.x + wa.z * f2.x + wa.w * f3.x
                  + wb.x * f4.x + wb.y * f5.x + wb.z * f6.x + wb.w * f7.x;
            acc1 += wa.x * f0.y + wa.y * f1.y + wa.z * f2.y + wa.w * f3.y
                  + wb.x * f4.y + wb.y * f5.y + wb.z * f6.y + wb.w * f7.y;
        }
        for (; e + 4 <= s1; e += 4) {
            float4 w4 = *(const float4*)(wpb + (e - s0a));
            int4 s4 = *(const int4*)(src + e);
            float2 f0 = __bfloat1622float2(vb[(size_t)s4.x * 64 + lane]);
            float2 f1 = __bfloat1622float2(vb[(size_t)s4.y * 64 + lane]);
            float2 f2 = __bfloat1622float2(vb[(size_t)s4.z * 64 + lane]);
            float2 f3 = __bfloat1622float2(vb[(size_t)s4.w * 64 + lane]);
            acc0 += w4.x * f0.x + w4.y * f1.x + w4.z * f2.x + w4.w * f3.x;
            acc1 += w4.x * f0.y + w4.y * f1.y + w4.z * f2.y + w4.w * f3.y;
        }
        for (; e < s1; ++e) {
            float w = wpb[e - s0a];
            float2 f = __bfloat1622float2(vb[(size_t)src[e] * 64 + lane]);
            acc0 += w * f.x; acc1 += w * f.y;
        }
    } else {
        float sum = 0.f;
        for (int e = s0 + i; e < s1; e += 16) sum += __expf(lp[e] - m);
        #pragma unroll
        for (int off = 8; off; off >>= 1) sum += __shfl_xor(sum, off);
        r = 1.0f / (sum + 1e-16f);

        int e = s0;
        for (; e < s1 && (e & 3); ++e) {
            float w = __expf(lp[e] - m);
            float2 f = __bfloat1622float2(vb[(size_t)src[e] * 64 + lane]);
            acc0 += w * f.x; acc1 += w * f.y;
        }
        for (; e + 8 <= s1; e += 8) {
            float4 la = *(const float4*)(lp + e);
            float4 lb = *(const float4*)(lp + e + 4);
            int4 sa = *(const int4*)(src + e);
            int4 sb = *(const int4*)(src + e + 4);
            float w0 = __expf(la.x - m), w1 = __expf(la.y - m);
            float w2 = __expf(la.z - m), w3 = __expf(la.w - m);
            float w4 = __expf(lb.x - m), w5 = __expf(lb.y - m);
            float w6 = __expf(lb.z - m), w7 = __expf(lb.w - m);
            float2 f0 = __bfloat1622float2(vb[(size_t)sa.x * 64 + lane]);
            float2 f1 = __bfloat1622float2(vb[(size_t)sa.y * 64 + lane]);
            float2 f2 = __bfloat1622float2(vb[(size_t)sa.z * 64 + lane]);
            float2 f3 = __bfloat1622float2(vb[(size_t)sa.w * 64 + lane]);
            float2 f4 = __bfloat1622float2(vb[(size_t)sb.x * 64 + lane]);
            float2 f5 = __bfloat1622float2(vb[(size_t)sb.y * 64 + lane]);
            float2 f6 = __bfloat1622float2(vb[(size_t)sb.z * 64 + lane]);
            float2 f7 = __bfloat1622float2(vb[(size_t)sb.w * 64 + lane]);
            acc0 += w0 * f0.x + w1 * f1.x + w2 * f2.x + w3 * f3.x
                  + w4 * f4.x + w5 * f5.x + w6 * f6.x + w7 * f7.x;
            acc1 += w0 * f0.y + w1 * f1.y + w2 * f2.y + w3 * f3.y
                  + w4 * f4.y + w5 * f5.y + w6 * f6.y + w7 * f7.y;
        }
        for (; e + 4 <= s1; e += 4) {
            float4 l4 = *(const float4*)(lp + e);
            int4 s4 = *(const int4*)(src + e);
            float w0 = __expf(l4.x - m);
            float w1 = __expf(l4.y - m);
            float w2 = __expf(l4.z - m);
            float w3 = __expf(l4.w - m);
            float2 f0 = __bfloat1622float2(vb[(size_t)s4.x * 64 + lane]);
            float2 f1 = __bfloat1622float2(vb[(size_t)s4.y * 64 + lane]);
            float2 f2 = __bfloat1622float2(vb[(size_t)s4.z * 64 + lane]);
            float2 f3 = __bfloat1622float2(vb[(size_t)s4.w * 64 + lane]);
            acc0 += w0 * f0.x + w1 * f1.x + w2 * f2.x + w3 * f3.x;
            acc1 += w0 * f0.y + w1 * f1.y + w2 * f2.y + w3 * f3.y;
        }
        for (; e < s1; ++e) {
            float w = __expf(lp[e] - m);
            float2 f = __bfloat1622float2(vb[(size_t)src[e] * 64 + lane]);
            acc0 += w * f.x; acc1 += w * f.y;
        }
    }
    *(float2*)(out + (size_t)q * 128 + lane * 2) = make_float2(acc0 * r, acc1 * r);
}

// ---------------------------------------------------------------------------
// ws layout: R0-proven; WvP planes past the high-water mark, runtime-checked.
// ---------------------------------------------------------------------------
extern "C" void kernel_launch(void* const* d_in, const int* in_sizes, int n_in,
                              void* d_out, int out_size, void* d_ws, size_t ws_size,
                              hipStream_t stream) {
    const float* h_obs     = (const float*)d_in[0];
    const float* pos_obs   = (const float*)d_in[1];
    const float* pos_query = (const float*)d_in[2];
    const int*   src       = (const int*)d_in[3];
    const int*   dst       = (const int*)d_in[4];
    const float* W1        = (const float*)d_in[5];
    const float* b1        = (const float*)d_in[6];
    const float* W2        = (const float*)d_in[7];
    const float* b2        = (const float*)d_in[8];
    const float* Wv        = (const float*)d_in[9];
    const float* bv        = (const float*)d_in[10];
    const float* log_sigma = (const float*)d_in[11];
    float* out = (float*)d_out;

    char* ws = (char*)d_ws;
    int*            rp      = (int*)(ws + 0);                   // 50001 ints  (end 200,004)
    float*          scal    = (float*)(ws + 200192);            // 8 floats    (end 200,224)
    unsigned short* W1cT    = (unsigned short*)(ws + 200256);   // 1024 bf16   (end 202,304)
    unsigned short* W2tb    = (unsigned short*)(ws + 202304);   // 512 bf16    (end 203,328)
    unsigned short* vbuf    = (unsigned short*)(ws + 208640);   // 6.4M bf16   (end 13,008,640)
    float*          logitsT = (float*)(ws + 13008768);          // 6.4M floats (end 38,608,768)
    unsigned short* WvPhi   = (unsigned short*)(ws + WVP_OFF);           // 32 KB
    unsigned short* WvPlo   = (unsigned short*)(ws + WVP_OFF + 32768);   // 32 KB

    int vp_mfma = (ws_size >= (size_t)WVP_OFF + WVP_BYTES) ? 1 : 0;

    hipLaunchKernelGGL(pack_kernel, dim3(9), dim3(256), 0, stream,
                       W1, b1, W2, b2, log_sigma, Wv, W1cT, W2tb, scal,
                       WvPhi, WvPlo, vp_mfma);
    hipLaunchKernelGGL(fused_kernel, dim3(EDGE_BLOCKS + VP_BLOCKS + RP_BLOCKS),
                       dim3(128), 0, stream,
                       pos_obs, pos_query, src, dst, W1cT, W2tb, scal, logitsT,
                       h_obs, Wv, bv, vbuf, rp, WvPhi, WvPlo, vp_mfma);
    hipLaunchKernelGGL(attn_kernel, dim3(N_Q / 4), dim3(256), 0, stream,
                       (const __hip_bfloat162*)vbuf, logitsT, src, rp, out);
}